// Round 14
// baseline (2605.667 us; speedup 1.0000x reference)
//
#include <hip/hip_runtime.h>

// LSTM encoder: V=32000 E=512 U=1024 L=2, B=64 T=256.
// Round 14: single-hop ALL-OBSERVE barrier (write-once slots => no WAR
// hazard => no release hop needed; each block polls all 64 group flags
// directly, thread t <-> flag t) + batch quartering (8 groups of 64 blocks:
// layer x quarter; fan-in 63). L1 polls the L0 group's arrive flags
// directly for its epoch (no mirror fan-out). U0/U1 register-resident;
// W1 streamed from L2 (1MB/XCD distinct, resident) in the overlap slot.
// r13's two-hop leader barrier (~2.5-3us) was the residual critical path.

typedef _Float16 f16;
typedef _Float16 f16x8 __attribute__((ext_vector_type(8)));
typedef _Float16 f16x4 __attribute__((ext_vector_type(4)));
typedef float f32x4 __attribute__((ext_vector_type(4)));

__device__ __forceinline__ f32x4 mfma16x32(f16x8 a, f16x8 b, f32x4 c) {
  return __builtin_amdgcn_mfma_f32_16x16x32_f16(a, b, c, 0, 0, 0);
}

__device__ __forceinline__ void gl_lds16(const void* g, void* l) {
  __builtin_amdgcn_global_load_lds(
      (const __attribute__((address_space(1))) void*)g,
      (__attribute__((address_space(3))) void*)l, 16, 0, 0);
}

__device__ __forceinline__ float sigmoidf_(float x) {
  return 1.0f / (1.0f + expf(-x));
}

// write-through stores: land at the L3 coherence point, no dirty L2 line
__device__ __forceinline__ void st_f16_sc(f16* p, float v) {
  f16 h = (f16)v;
  unsigned u = (unsigned)__builtin_bit_cast(unsigned short, h);
  asm volatile("global_store_short %0, %1, off sc0 sc1"
               :: "v"(p), "v"(u) : "memory");
}
__device__ __forceinline__ void st_b128_sc(f16* p, f16x8 v) {
  asm volatile("global_store_dwordx4 %0, %1, off sc0 sc1"
               :: "v"(p), "v"(v) : "memory");
}

__device__ __forceinline__ unsigned ld_flag(const unsigned* p) {
  return __hip_atomic_load(p, __ATOMIC_RELAXED, __HIP_MEMORY_SCOPE_AGENT);
}
__device__ __forceinline__ void st_flag(unsigned* p, unsigned v) {
  __hip_atomic_store(p, v, __ATOMIC_RELAXED, __HIP_MEMORY_SCOPE_AGENT);
}

// ---------- transpose + cast: D[n][k] = (f16)S[k][n] ----------
__global__ __launch_bounds__(256) void k_transpose_f16(
    const float* __restrict__ S, f16* __restrict__ D, int K, int N) {
  __shared__ float tile[64][65];
  int nk = K >> 6;
  int k0 = (blockIdx.x % nk) << 6;
  int n0 = (blockIdx.x / nk) << 6;
  int tc = threadIdx.x & 63;
  int tq = threadIdx.x >> 6;
#pragma unroll
  for (int r = 0; r < 16; ++r) {
    int kk = tq * 16 + r;
    tile[kk][tc] = S[(size_t)(k0 + kk) * N + (n0 + tc)];
  }
  __syncthreads();
#pragma unroll
  for (int r = 0; r < 16; ++r) {
    int nn = tq * 16 + r;
    D[(size_t)(n0 + nn) * K + (k0 + tc)] = (f16)tile[tc][nn];
  }
}

// ---------- embedding lookup -> fp16 A0[m][512], row m = t*64 + b ----------
__global__ __launch_bounds__(256) void k_embed_f16(
    const int* __restrict__ tok, const float* __restrict__ emb,
    f16* __restrict__ A0) {
  int i = blockIdx.x * 256 + threadIdx.x;
  int m = i >> 7;
  int e = (i & 127) << 2;
  int t = m >> 6, b = m & 63;
  int tk = tok[b * 256 + t];
  const float4 v = *(const float4*)(emb + (size_t)tk * 512 + e);
  f16x4 o = {(f16)v.x, (f16)v.y, (f16)v.z, (f16)v.w};
  *(f16x4*)(A0 + (size_t)m * 512 + e) = o;
}

// ---------- C[m][n] = (f16)(sum_k A[m][k]*Bt[n][k] + bias[n]) ----------
__global__ __launch_bounds__(256) void k_gemm_f16(
    const f16* __restrict__ A, const f16* __restrict__ Bt,
    const float* __restrict__ bias, f16* __restrict__ C,
    int M, int N, int K) {
  __shared__ f16 sA[2][128 * 32];
  __shared__ f16 sB[2][128 * 32];
  const int tid = threadIdx.x, lane = tid & 63, w = tid >> 6;
  const int mb = M >> 7;
  const int bm = blockIdx.x % mb, bn = blockIdx.x / mb;
  const int am0 = bm << 7, bn0 = bn << 7;
  const int wm = w >> 1, wn = w & 1;
  const int srow = lane >> 2, sch = lane & 3;

  f32x4 acc[4][4] = {};
  const int NT = K >> 5;
  int cur = 0;

  auto stage = [&](int kt, int buf) {
#pragma unroll
    for (int q2 = 0; q2 < 2; ++q2) {
      int q = w * 2 + q2;
      int row = q * 16 + srow;
      const f16* ga = A + (size_t)(am0 + row) * K + kt * 32 + sch * 8;
      const f16* gb = Bt + (size_t)(bn0 + row) * K + kt * 32 + sch * 8;
      gl_lds16(ga, (char*)&sA[buf][0] + q * 1024);
      gl_lds16(gb, (char*)&sB[buf][0] + q * 1024);
    }
  };

  stage(0, 0);
  __syncthreads();
  for (int kt = 0; kt < NT; ++kt) {
    if (kt + 1 < NT) stage(kt + 1, cur ^ 1);
    const f16* pa = &sA[cur][(wm * 64 + (lane & 15)) * 32 + (lane >> 4) * 8];
    const f16* pb = &sB[cur][(wn * 64 + (lane & 15)) * 32 + (lane >> 4) * 8];
    f16x8 av[4], bv[4];
#pragma unroll
    for (int mf = 0; mf < 4; ++mf) av[mf] = *(const f16x8*)(pa + mf * 512);
#pragma unroll
    for (int nf = 0; nf < 4; ++nf) bv[nf] = *(const f16x8*)(pb + nf * 512);
#pragma unroll
    for (int mf = 0; mf < 4; ++mf)
#pragma unroll
      for (int nf = 0; nf < 4; ++nf)
        acc[mf][nf] = mfma16x32(av[mf], bv[nf], acc[mf][nf]);
    __syncthreads();
    cur ^= 1;
  }

#pragma unroll
  for (int mf = 0; mf < 4; ++mf)
#pragma unroll
    for (int nf = 0; nf < 4; ++nf) {
      int col = bn0 + wn * 64 + nf * 16 + (lane & 15);
      float bs = bias[col];
#pragma unroll
      for (int r = 0; r < 4; ++r) {
        int row = am0 + wm * 64 + mf * 16 + (lane >> 4) * 4 + r;
        C[(size_t)row * N + col] = (f16)(acc[mf][nf][r] + bs);
      }
    }
}

// ---------- quarter-group scan, single-hop all-observe barrier ----------
// 512 blocks x 256 thr. l = bid>>8 (layer), rb = bid&255, q = rb>>6
// (batch quarter: rows q*16..q*16+16), i = rb&63 (group id),
// cc = (i&7)*8 + i>>3 (col chunk, XCD-local: cc>>3 == i&7 == XCD),
// units [cc*16, cc*16+16) x 4 gates = 64 cols/block. Groups (l,q): 64
// blocks, 64 arrive flags, no leader/release.
__global__ __launch_bounds__(256, 2) void k_scan8(
    const f16* __restrict__ XZ, const f16* __restrict__ U0t,
    const f16* __restrict__ W1t, const f16* __restrict__ U1t,
    const float* __restrict__ b1, f16* __restrict__ A1,
    f16* __restrict__ H1h, float* __restrict__ out, unsigned* arr) {
  __shared__ float zred[4224];  // 4 waves x 16 rows x stride 66
  __shared__ __align__(16) f16 hstage[16][16];
  const int tid = threadIdx.x, lane = tid & 63, w = tid >> 6;
  const int j = lane & 15, kg = lane >> 4;
  const int l = (int)blockIdx.x >> 8;
  const int rb = (int)blockIdx.x & 255;
  const int q = rb >> 6, i = rb & 63;
  const int cc = ((i & 7) << 3) + (i >> 3);
  const int u0 = cc * 16, row0 = q * 16;
  const int wko = w * 256 + kg * 8;
  const int aoff = (row0 + j) * 1024 + wko;
  const int erl = tid >> 4, eunit = tid & 15;
  const int erow = row0 + erl, eu = u0 + eunit;
  unsigned* gArr = arr + (size_t)((l * 4 + q) * 64) * 32;
  unsigned* l0Arr = arr + (size_t)(q * 64) * 32;

  // resident recurrent weights (U0 for L0, U1 for L1): 4 col-sets x 8 kt
  f16x8 bv[4][8];
  {
    const f16* RW = l ? U1t : U0t;
#pragma unroll
    for (int n = 0; n < 4; ++n) {
      const f16* bp = RW + (size_t)(n * 1024 + u0 + j) * 1024 + wko;
#pragma unroll
      for (int kt = 0; kt < 8; ++kt)
        bv[n][kt] = *(const f16x8*)(bp + kt * 32);
    }
  }
  float c = 0.0f;  // this thread's (row,unit) cell state

  if (l == 0) {
    // ================= layer 0 =================
    float xz[4];
#pragma unroll
    for (int g = 0; g < 4; ++g)
      xz[g] = (float)XZ[(size_t)erow * 4096 + g * 1024 + eu];

    for (int s = 0; s < 256; ++s) {
      f32x4 acc[4] = {};
      if (s > 0) {
        const f16* ap = A1 + (size_t)(s - 1) * 65536 + aoff;
#pragma unroll
        for (int kt = 0; kt < 8; ++kt) {
          f16x8 av = *(const f16x8*)(ap + kt * 32);
#pragma unroll
          for (int n = 0; n < 4; ++n)
            acc[n] = mfma16x32(av, bv[n][kt], acc[n]);
        }
      }
#pragma unroll
      for (int n = 0; n < 4; ++n)
#pragma unroll
        for (int r = 0; r < 4; ++r)
          zred[w * 1056 + (kg * 4 + r) * 66 + n * 16 + j] = acc[n][r];
      __syncthreads();
      float z[4];
#pragma unroll
      for (int g = 0; g < 4; ++g) {
        float sm = xz[g];
#pragma unroll
        for (int wv = 0; wv < 4; ++wv)
          sm += zred[wv * 1056 + erl * 66 + g * 16 + eunit];
        z[g] = sm;
      }
      float gi = sigmoidf_(z[0]), gf = sigmoidf_(z[1]);
      float gg = tanhf(z[2]), go = sigmoidf_(z[3]);
      c = gf * c + gi * gg;
      hstage[erl][eunit] = (f16)(go * tanhf(c));
      __syncthreads();
      if (tid < 32)
        st_b128_sc(&A1[(size_t)(s * 64 + row0 + (tid >> 1)) * 1024 + u0 +
                       (tid & 1) * 8],
                   *(const f16x8*)&hstage[tid >> 1][(tid & 1) * 8]);
      asm volatile("s_waitcnt vmcnt(0)" ::: "memory");
      __syncthreads();  // h stores at L3

      const unsigned v = (unsigned)s + 1u;
      if (tid == 0) st_flag(&gArr[(unsigned)i * 32u], v);  // arrive
      // prefetch next xz under the poll
      float xzn[4] = {0.f, 0.f, 0.f, 0.f};
      if (s + 1 < 256) {
        const f16* xrow = XZ + (size_t)((s + 1) * 64 + erow) * 4096;
#pragma unroll
        for (int g = 0; g < 4; ++g) xzn[g] = (float)xrow[g * 1024 + eu];
      }
      if (tid < 64) {  // observe all 64 arrivals directly
        while (ld_flag(&gArr[(unsigned)tid * 32u]) < v)
          __builtin_amdgcn_s_sleep(1);
      }
      __syncthreads();
#pragma unroll
      for (int g = 0; g < 4; ++g) xz[g] = xzn[g];
    }
  } else {
    // ================= layer 1 =================
    float bias1[4];
#pragma unroll
    for (int g = 0; g < 4; ++g) bias1[g] = b1[g * 1024 + eu];
    const f16* w1p[4];
#pragma unroll
    for (int n = 0; n < 4; ++n)
      w1p[n] = W1t + (size_t)(n * 1024 + u0 + j) * 1024 + wko;

    // prime: wait for L0 epoch 1, compute accW = W1 * h0(0)
    if (tid < 64) {
      while (ld_flag(&l0Arr[(unsigned)tid * 32u]) < 1u)
        __builtin_amdgcn_s_sleep(1);
    }
    __syncthreads();
    f32x4 accW[4] = {};
    {
      const f16* ap = A1 + aoff;
#pragma unroll
      for (int kt = 0; kt < 8; ++kt) {
        f16x8 av = *(const f16x8*)(ap + kt * 32);
#pragma unroll
        for (int n = 0; n < 4; ++n)
          accW[n] = mfma16x32(av, *(const f16x8*)(w1p[n] + kt * 32),
                              accW[n]);
      }
    }

    for (int t = 0; t < 256; ++t) {
      f32x4 acc[4] = {accW[0], accW[1], accW[2], accW[3]};
      if (t > 0) {
        const f16* hp = H1h + (size_t)(t - 1) * 65536 + aoff;
#pragma unroll
        for (int kt = 0; kt < 8; ++kt) {
          f16x8 av = *(const f16x8*)(hp + kt * 32);
#pragma unroll
          for (int n = 0; n < 4; ++n)
            acc[n] = mfma16x32(av, bv[n][kt], acc[n]);
        }
      }
#pragma unroll
      for (int n = 0; n < 4; ++n)
#pragma unroll
        for (int r = 0; r < 4; ++r)
          zred[w * 1056 + (kg * 4 + r) * 66 + n * 16 + j] = acc[n][r];
      __syncthreads();
      float z[4];
#pragma unroll
      for (int g = 0; g < 4; ++g) {
        float sm = bias1[g];
#pragma unroll
        for (int wv = 0; wv < 4; ++wv)
          sm += zred[wv * 1056 + erl * 66 + g * 16 + eunit];
        z[g] = sm;
      }
      float gi = sigmoidf_(z[0]), gf = sigmoidf_(z[1]);
      float gg = tanhf(z[2]), go = sigmoidf_(z[3]);
      c = gf * c + gi * gg;
      float hn = go * tanhf(c);
      if (t == 255) {
        out[(size_t)erow * 262144 + (size_t)t * 1024 + eu] = hn;
        out[16777216 + erow * 1024 + eu] = hn;
        out[16777216 + 65536 + erow * 1024 + eu] = c;
        break;  // last step: no publish/barrier needed
      }
      hstage[erl][eunit] = (f16)hn;
      __syncthreads();
      if (tid < 32)
        st_b128_sc(&H1h[(size_t)t * 65536 + (row0 + (tid >> 1)) * 1024 + u0 +
                        (tid & 1) * 8],
                   *(const f16x8*)&hstage[tid >> 1][(tid & 1) * 8]);
      asm volatile("s_waitcnt vmcnt(0)" ::: "memory");
      __syncthreads();  // h stores at L3

      const unsigned v = (unsigned)t + 1u;
      if (tid == 0) st_flag(&gArr[(unsigned)i * 32u], v);  // arrive
      // deferred out store hides under the poll
      out[(size_t)erow * 262144 + (size_t)t * 1024 + eu] = hn;
      if (tid < 64) {  // own group: peers' h1(t) written
        while (ld_flag(&gArr[(unsigned)tid * 32u]) < v)
          __builtin_amdgcn_s_sleep(1);
      } else if (tid < 128) {  // L0 group: A1[t+1] written (epoch t+2)
        while (ld_flag(&l0Arr[(unsigned)(tid - 64) * 32u]) < v + 1u)
          __builtin_amdgcn_s_sleep(1);
      }
      __syncthreads();
      // overlap slot: next step's W1 pass (W1 streamed from L2)
      {
        const f16* ap = A1 + (size_t)(t + 1) * 65536 + aoff;
        f32x4 tw[4] = {};
#pragma unroll
        for (int kt = 0; kt < 8; ++kt) {
          f16x8 av = *(const f16x8*)(ap + kt * 32);
#pragma unroll
          for (int n = 0; n < 4; ++n)
            tw[n] = mfma16x32(av, *(const f16x8*)(w1p[n] + kt * 32), tw[n]);
        }
#pragma unroll
        for (int n = 0; n < 4; ++n) accW[n] = tw[n];
      }
    }
  }
}

// ---------- fallback: fused per-step kernel (r9/r10, proven) ----------
__device__ __forceinline__ void reduce4(const f32x4 acc[4], float* zred,
                                        float z[4]) {
  const int tid = threadIdx.x, lane = tid & 63, w = tid >> 6;
  const int j = lane & 15, kg = lane >> 4;
#pragma unroll
  for (int mf = 0; mf < 4; ++mf)
#pragma unroll
    for (int r = 0; r < 4; ++r)
      zred[w * 1088 + (mf * 16 + kg * 4 + r) * 17 + j] = acc[mf][r];
  __syncthreads();
  const int erow = tid >> 2, euu = tid & 3;
#pragma unroll
  for (int g = 0; g < 4; ++g) {
#pragma unroll
    for (int wv = 0; wv < 4; ++wv)
      z[g] += zred[wv * 1088 + erow * 17 + g * 4 + euu];
  }
}

__device__ __forceinline__ void step_once(
    int s, int u0, const f16x8 bvU0[8], const f16x8 bvW1[8],
    const f16x8 bvU1[8], const float bias1[4], const float xz[4],
    f16* __restrict__ A1, f16* __restrict__ H1h, int hmask,
    float& c0, float& c1, float* __restrict__ out, float* zred) {
  const int tid = threadIdx.x, lane = tid & 63, w = tid >> 6;
  const int j = lane & 15, kg = lane >> 4;
  const int aoff = j * 1024 + w * 256 + kg * 8;
  const int erow = tid >> 2;
  const int eu = u0 + (tid & 3);

  f32x4 accA[4] = {};
  f32x4 accB[4] = {};

  if (s >= 1) {
    const f16* ap = A1 + (size_t)(s - 1) * 65536 + aoff;
#pragma unroll
    for (int kt = 0; kt < 8; ++kt)
#pragma unroll
      for (int mf = 0; mf < 4; ++mf) {
        f16x8 av = *(const f16x8*)(ap + mf * 16384 + kt * 32);
        if (s < 256) accA[mf] = mfma16x32(av, bvU0[kt], accA[mf]);
        accB[mf] = mfma16x32(av, bvW1[kt], accB[mf]);
      }
    if (s >= 2) {
      const f16* hp = H1h + (size_t)((s - 2) & hmask) * 65536 + aoff;
#pragma unroll
      for (int kt = 0; kt < 8; ++kt)
#pragma unroll
        for (int mf = 0; mf < 4; ++mf)
          accB[mf] = mfma16x32(*(const f16x8*)(hp + mf * 16384 + kt * 32),
                               bvU1[kt], accB[mf]);
    }
  }

  if (s < 256) {
    float z[4] = {xz[0], xz[1], xz[2], xz[3]};
    reduce4(accA, zred, z);
    float gi = sigmoidf_(z[0]), gf = sigmoidf_(z[1]);
    float gg = tanhf(z[2]), go = sigmoidf_(z[3]);
    c0 = gf * c0 + gi * gg;
    st_f16_sc(&A1[(size_t)(s * 64 + erow) * 1024 + eu], go * tanhf(c0));
  }
  __syncthreads();

  if (s >= 1) {
    const int t = s - 1;
    float z[4] = {bias1[0], bias1[1], bias1[2], bias1[3]};
    reduce4(accB, zred, z);
    float gi = sigmoidf_(z[0]), gf = sigmoidf_(z[1]);
    float gg = tanhf(z[2]), go = sigmoidf_(z[3]);
    c1 = gf * c1 + gi * gg;
    float hn = go * tanhf(c1);
    st_f16_sc(&H1h[(size_t)(t & hmask) * 65536 + erow * 1024 + eu], hn);
    out[(size_t)erow * 262144 + (size_t)t * 1024 + eu] = hn;
    if (t == 255) {
      out[16777216 + erow * 1024 + eu] = hn;
      out[16777216 + 65536 + erow * 1024 + eu] = c1;
    }
  }
}

__global__ __launch_bounds__(256, 1) void k_step(
    const f16* __restrict__ XZ, const f16* __restrict__ U0t,
    const f16* __restrict__ W1t, const f16* __restrict__ U1t,
    const float* __restrict__ b1, f16* __restrict__ A1,
    f16* __restrict__ H1h, float* __restrict__ C0, float* __restrict__ C1,
    float* __restrict__ out, int s) {
  __shared__ float zred[4352];
  const int tid_ = threadIdx.x, lane_ = tid_ & 63, w_ = tid_ >> 6;
  const int bid_ = (int)blockIdx.x;
  const int i_ = ((bid_ & 7) << 5) + (bid_ >> 3);
  const int u0 = i_ * 4;
  const int j_ = lane_ & 15;
  const int kg_ = lane_ >> 4;
  const int ncol_ = (j_ >> 2) * 1024 + u0 + (j_ & 3);
  const int woff_ = ncol_ * 1024 + w_ * 256 + kg_ * 8;
  f16x8 bvU0[8], bvW1[8], bvU1[8];
#pragma unroll
  for (int kt = 0; kt < 8; ++kt) {
    bvU0[kt] = *(const f16x8*)(U0t + woff_ + kt * 32);
    bvW1[kt] = *(const f16x8*)(W1t + woff_ + kt * 32);
    bvU1[kt] = *(const f16x8*)(U1t + woff_ + kt * 32);
  }
  const int erow_ = tid_ >> 2;
  const int eu_ = u0 + (tid_ & 3);
  float bias1[4];
#pragma unroll
  for (int g = 0; g < 4; ++g) bias1[g] = b1[g * 1024 + eu_];

  float xz[4] = {0.f, 0.f, 0.f, 0.f};
  if (s < 256) {
    const f16* xrow = XZ + (size_t)(s * 64 + erow_) * 4096;
#pragma unroll
    for (int g = 0; g < 4; ++g) xz[g] = (float)xrow[g * 1024 + eu_];
  }
  float c0 = C0[erow_ * 1024 + eu_];
  float c1 = C1[erow_ * 1024 + eu_];
  step_once(s, u0, bvU0, bvW1, bvU1, bias1, xz, A1, H1h, 1, c0, c1, out,
            zred);
  C0[erow_ * 1024 + eu_] = c0;
  C1[erow_ * 1024 + eu_] = c1;
}

extern "C" void kernel_launch(void* const* d_in, const int* in_sizes, int n_in,
                              void* d_out, int out_size, void* d_ws, size_t ws_size,
                              hipStream_t stream) {
  (void)in_sizes; (void)n_in; (void)out_size;
  const int* tokens = (const int*)d_in[0];
  const float* emb = (const float*)d_in[1];
  const float* W0 = (const float*)d_in[2];
  const float* U0 = (const float*)d_in[3];
  const float* b0 = (const float*)d_in[4];
  const float* W1 = (const float*)d_in[5];
  const float* U1 = (const float*)d_in[6];
  const float* b1 = (const float*)d_in[7];
  float* out = (float*)d_out;

  // workspace carve-up; H1h LAST (coop path needs the full 256 slots)
  char* p = (char*)d_ws;
  f16* A0 = (f16*)p;   p += (size_t)16384 * 512 * 2;    // x tokens, fp16
  f16* A1 = (f16*)p;   p += (size_t)16384 * 1024 * 2;   // h0 history
  f16* W0t = (f16*)p;  p += (size_t)4096 * 512 * 2;     // W0^T
  f16* U0t = (f16*)p;  p += (size_t)4096 * 1024 * 2;    // U0^T
  f16* W1t = (f16*)p;  p += (size_t)4096 * 1024 * 2;    // W1^T
  f16* U1t = (f16*)p;  p += (size_t)4096 * 1024 * 2;    // U1^T
  f16* XZ = (f16*)p;   p += (size_t)16384 * 4096 * 2;   // xz0, rows t*64+b
  float* C0 = (float*)p; p += 64 * 1024 * 4;            // cell L0 (fallback)
  float* C1 = (float*)p; p += 64 * 1024 * 4;            // cell L1 (fallback)
  unsigned* arr = (unsigned*)p; p += 8 * 64 * 32 * 4;   // arrive lines (8 grp)
  f16* H1h = (f16*)p;                                   // h1 history slots
  const size_t need_coop = (size_t)(p - (char*)d_ws) + (size_t)256 * 65536 * 2;

  // weight transposes + casts
  k_transpose_f16<<<512, 256, 0, stream>>>(W0, W0t, 512, 4096);
  k_transpose_f16<<<1024, 256, 0, stream>>>(U0, U0t, 1024, 4096);
  k_transpose_f16<<<1024, 256, 0, stream>>>(W1, W1t, 1024, 4096);
  k_transpose_f16<<<1024, 256, 0, stream>>>(U1, U1t, 1024, 4096);

  // embedding
  k_embed_f16<<<8192, 256, 0, stream>>>(tokens, emb, A0);

  // layer 0 input projection: xz0 = x @ W0 + b0
  k_gemm_f16<<<4096, 256, 0, stream>>>(A0, W0t, b0, XZ, 16384, 4096, 512);

  hipMemsetAsync(C0, 0, 64 * 1024 * 4 * 2, stream);  // C0+C1
  hipMemsetAsync(arr, 0, 8 * 64 * 32 * 4, stream);   // flags

  bool coop_ok = (ws_size >= need_coop);
  if (coop_ok) {
    const f16* XZc = XZ; const f16* U0c = U0t; const f16* W1c = W1t;
    const f16* U1c = U1t; const float* b1c = b1;
    f16* A1p = A1; f16* H1p = H1h; float* outp = out;
    unsigned* ar = arr;
    void* kargs[] = {(void*)&XZc, (void*)&U0c, (void*)&W1c, (void*)&U1c,
                     (void*)&b1c, (void*)&A1p, (void*)&H1p, (void*)&outp,
                     (void*)&ar};
    hipError_t e = hipLaunchCooperativeKernel((const void*)k_scan8, dim3(512),
                                              dim3(256), kargs, 0, stream);
    if (e != hipSuccess) {
      (void)hipGetLastError();
      coop_ok = false;
    }
  }
  if (!coop_ok) {
    for (int s = 0; s <= 256; ++s)
      k_step<<<256, 256, 0, stream>>>(XZ, U0t, W1t, U1t, b1, A1, H1h, C0, C1,
                                      out, s);
  }
}